// Round 4
// baseline (179.911 us; speedup 1.0000x reference)
//
#include <hip/hip_runtime.h>
#include <cstdint>
#include <cstddef>

typedef unsigned short u16;
typedef __attribute__((ext_vector_type(8))) short s16x8;
typedef __attribute__((ext_vector_type(8))) u16 u16x8;
typedef __attribute__((ext_vector_type(4))) float f32x4;

#define DEV static __device__ __forceinline__
#define GPTR(p) (const __attribute__((address_space(1))) void*)(p)
#define LPTR(p) (__attribute__((address_space(3))) void*)(p)
#define LGKM0 asm volatile("s_waitcnt lgkmcnt(0)" ::: "memory")
#define SCHEDB __builtin_amdgcn_sched_barrier(0)
#define BAR __builtin_amdgcn_s_barrier()

DEV float b2f(u16 u) { union { unsigned i; float f; } c; c.i = ((unsigned)u) << 16; return c.f; }
DEV u16 f2b(float f) {
  union { float f; unsigned i; } c; c.f = f;
  unsigned r = (c.i + 0x7fffu + ((c.i >> 16) & 1u)) >> 16;
  return (u16)r;
}
DEV float sigm(float x) { return 1.0f / (1.0f + __expf(-x)); }

// ---------------------------------------------------------------------------
// Pack gate weights (f32 in) into concatenated bf16 [N,1536]:
//   WZR rows 0..1023    = [W_xz | W_hz | W_mz]
//   WZR rows 1024..2047 = [W_xr | W_hr | W_mr]
//   WH  rows 0..1023    = [W_xh | W_hh | W_mh]
// plus bf16 copy of W_gamma_h -> WGH [1024,256].
// ---------------------------------------------------------------------------
__global__ __launch_bounds__(256) void pack_w(
    const float* __restrict__ Wxz, const float* __restrict__ Whz, const float* __restrict__ Wmz,
    const float* __restrict__ Wxr, const float* __restrict__ Whr, const float* __restrict__ Wmr,
    const float* __restrict__ Wxh, const float* __restrict__ Whh, const float* __restrict__ Wmh,
    const float* __restrict__ Wgh,
    u16* __restrict__ WZR, u16* __restrict__ WH, u16* __restrict__ WGH)
{
  int t = blockIdx.x * 256 + threadIdx.x;
  const float* src;
  u16* dst;
  if (t < 589824) {
    int row = t / 192;
    int col = (t % 192) * 8;
    int rr = row & 1023;
    const float *wx, *wh, *wm;
    if (row < 1024)      { wx = Wxz; wh = Whz; wm = Wmz; }
    else if (row < 2048) { wx = Wxr; wh = Whr; wm = Wmr; }
    else                 { wx = Wxh; wh = Whh; wm = Wmh; }
    if (col < 256)       src = wx + rr * 256 + col;
    else if (col < 1280) src = wh + (size_t)rr * 1024 + (col - 256);
    else                 src = wm + rr * 256 + (col - 1280);
    dst = (row < 2048) ? (WZR + (size_t)row * 1536 + col)
                       : (WH + (size_t)(row - 2048) * 1536 + col);
  } else {
    int t2 = t - 589824;
    src = Wgh + t2 * 8;
    dst = WGH + t2 * 8;
  }
  f32x4 a = *(const f32x4*)src;
  f32x4 b = *(const f32x4*)(src + 4);
  u16x8 v;
#pragma unroll
  for (int j = 0; j < 4; ++j) { v[j] = f2b(a[j]); v[j + 4] = f2b(b[j]); }
  *(u16x8*)dst = v;
}

// ---------------------------------------------------------------------------
// Elementwise over [B,D]: gamma_x, imputation, x_hat -> X1 cols 0..255 and
// 1280..1535 (m), bf16 delta copy, f32 x_last_obs_new.
// ---------------------------------------------------------------------------
__global__ __launch_bounds__(256) void elem_k(
    const float* __restrict__ x, const float* __restrict__ m, const float* __restrict__ delta,
    const float* __restrict__ xlo, const float* __restrict__ x_mean,
    const float* __restrict__ Wgx, const float* __restrict__ bgx,
    u16* __restrict__ X1, u16* __restrict__ Dbf,
    float* __restrict__ out_xlo)
{
  int t = blockIdx.x * 256 + threadIdx.x;
  int row = t >> 5;
  int col = (t & 31) * 8;
  size_t base = (size_t)row * 256 + col;
  u16x8 vxhat, vm16, vd16;
  f32x4 vlnew[2];
#pragma unroll
  for (int half = 0; half < 2; ++half) {
    f32x4 vx = *(const f32x4*)(x + base + half * 4);
    f32x4 vm = *(const f32x4*)(m + base + half * 4);
    f32x4 vd = *(const f32x4*)(delta + base + half * 4);
    f32x4 vl = *(const f32x4*)(xlo + base + half * 4);
    f32x4 vmean = *(const f32x4*)(x_mean + col + half * 4);
    f32x4 vwg = *(const f32x4*)(Wgx + col + half * 4);
    f32x4 vbg = *(const f32x4*)(bgx + col + half * 4);
#pragma unroll
    for (int j = 0; j < 4; ++j) {
      float mf = vm[j];
      float lnew = (mf > 0.5f) ? vx[j] : vl[j];
      vlnew[half][j] = lnew;
      float gx = __expf(-fmaxf(vd[j] * vwg[j] + vbg[j], 0.0f));
      float ximp = gx * lnew + (1.0f - gx) * vmean[j];
      float xhat = mf * vx[j] + (1.0f - mf) * ximp;
      vxhat[half * 4 + j] = f2b(xhat);
      vm16[half * 4 + j] = f2b(mf);
      vd16[half * 4 + j] = f2b(vd[j]);
    }
  }
  size_t r1536 = (size_t)row * 1536;
  *(u16x8*)(X1 + r1536 + col) = vxhat;
  *(u16x8*)(X1 + r1536 + 1280 + col) = vm16;
  *(u16x8*)(Dbf + base) = vd16;
  *(f32x4*)(out_xlo + base) = vlnew[0];
  *(f32x4*)(out_xlo + base + 4) = vlnew[1];
}

// ---------------------------------------------------------------------------
// Single-barrier-per-phase pipelined bf16 GEMM: C = A[M,K] @ W[N,K]^T.
// BN=256, BM=MF*32, BK=64, 8 waves (2Mx4N). 4 phases per K-tile:
//   phase = { lgkmcnt(0) ; MFMA cluster ; prefetch NEXT phase's ds_reads ;
//             stage one k-half unit ; [counted vmcnt] ; s_barrier }
// ds_reads complete under the NEXT phase's MFMA+barrier; DMA stages overlap
// MFMA of other waves (no lockstep window). Slot epochs (single barrier):
//   reads of slot S retire at lgkm of phase p -> certified by p's barrier ->
//   restage >= p+1 -> drained (vmcnt) + barrier before next read-prefetch.
// MF=8: phases (ks,mq); stages A(t+1,k1),B(t+1,k1),A(t+2,k0),B(t+2,k0);
//       vmcnt(6) at ph0/ph2.      MF=4: phases (ks,nh); vmcnt(4) at ph0/ph2.
// Swizzle (verified 0-conflict): 16B chunk ^= (row>>1)&3; linear LDS dest +
// inverse-swizzled global source + swizzled ds_read. XCD-bijective block map.
// EPI 0: h_decayed = exp(-relu(.+bgh)) * h      -> X1 cols 256..1279 (bf16)
// EPI 1: cols<1024: z=sigmoid -> Z ; cols>=1024: r*hdec -> RH (bf16)
// EPI 2: h_new = (1-z)*hdec + z*tanh(.+bmh)     -> d_out (f32)
//        (EPI2 A-operand: X1 for k<256 & k>=1280, RH for middle cols)
// ---------------------------------------------------------------------------
template<int EPI, int MF>
__global__ __launch_bounds__(512, 2) void gemm_bt(
    const u16* __restrict__ A, const u16* __restrict__ A2, int K,
    const u16* __restrict__ W,
    const float* __restrict__ bias0, const float* __restrict__ bias1,
    const float* __restrict__ auxf,  // EPI0: h (f32)
    const u16* __restrict__ auxb,    // EPI1/2: X1 (hdec source, bf16)
    const u16* __restrict__ aux2b,   // EPI2: Z (bf16)
    u16* __restrict__ out0b,         // EPI0: X1 ; EPI1: Z
    u16* __restrict__ out1b,         // EPI1: RH
    float* __restrict__ outf)        // EPI2: d_out h_new
{
  constexpr int BM = MF * 32;
  constexpr int GX = (MF == 8) ? 8 : 4;
  constexpr int AL = MF / 4;               // A-stage instrs per wave per unit
  __shared__ alignas(16) u16 As[2][2][BM * 32];
  __shared__ alignas(16) u16 Bs[2][2][256 * 32];

  const int tid = threadIdx.x;
  const int lane = tid & 63;
  const int wave = tid >> 6;
  const int wr = wave >> 2;                // 0..1 (M)
  const int wc = wave & 3;                 // 0..3 (N)

  // bijective XCD swizzle: 32 consecutive logical blocks per XCD
  const int d = blockIdx.y * GX + blockIdx.x;
  const int L = ((d & 7) << 5) | (d >> 3);
  const int brow = (L / GX) * BM;
  const int bcol = (L % GX) * 256;
  const int NT = K / 64;

  const int lr = lane & 15, g4 = lane >> 4;
  const int rchunk = ((g4 ^ ((lr >> 1) & 3)) * 8);   // swizzled read chunk
  const int sr16 = lane >> 2;                        // staging row in 16-block
  const int scs = (lane & 3) ^ ((sr16 >> 1) & 3);    // inverse-swizzled src chunk

  f32x4 acc[MF][4];
#pragma unroll
  for (int i = 0; i < MF; ++i)
#pragma unroll
    for (int j = 0; j < 4; ++j) { f32x4 z0 = {0.f, 0.f, 0.f, 0.f}; acc[i][j] = z0; }

  auto stA = [&](int st, int bu, int kh) {
    int stc = st < NT ? st : NT - 1;       // tail clamp: dummy into dead slot
    const u16* Ab; size_t Astr; int co;
    if constexpr (EPI == 2) {
      if (stc >= 4 && stc < 20) { Ab = A2; Astr = 1024; co = stc * 64 + kh * 32 - 256; }
      else                      { Ab = A;  Astr = 1536; co = stc * 64 + kh * 32; }
    } else { Ab = A; Astr = (size_t)K; co = stc * 64 + kh * 32; }
#pragma unroll
    for (int q = 0; q < AL; ++q) {
      int rb = (q * 8 + wave) * 16;
      __builtin_amdgcn_global_load_lds(
          GPTR(Ab + (size_t)(brow + rb + sr16) * Astr + co + scs * 8),
          LPTR(&As[bu][kh][rb * 32]), 16, 0, 0);
    }
  };
  auto stB = [&](int st, int bu, int kh) {
    int stc = st < NT ? st : NT - 1;
    int co = stc * 64 + kh * 32;
#pragma unroll
    for (int q = 0; q < 2; ++q) {
      int rb = (q * 8 + wave) * 16;
      __builtin_amdgcn_global_load_lds(
          GPTR(W + (size_t)(bcol + rb + sr16) * (size_t)K + co + scs * 8),
          LPTR(&Bs[bu][kh][rb * 32]), 16, 0, 0);
    }
  };
  auto LDA4 = [&](s16x8* dst, int bu, int ks, int mq) {
#pragma unroll
    for (int ii = 0; ii < 4; ++ii)
      dst[ii] = *(const s16x8*)&As[bu][ks][(wr * (BM / 2) + mq * 64 + ii * 16 + lr) * 32 + rchunk];
  };
  auto LDB4 = [&](s16x8* dst, int bu, int ks) {
#pragma unroll
    for (int j = 0; j < 4; ++j)
      dst[j] = *(const s16x8*)&Bs[bu][ks][(wc * 64 + j * 16 + lr) * 32 + rchunk];
  };
  auto LDB2 = [&](s16x8* dst, int bu, int ks, int nh) {
#pragma unroll
    for (int j = 0; j < 2; ++j)
      dst[j] = *(const s16x8*)&Bs[bu][ks][(wc * 64 + nh * 32 + j * 16 + lr) * 32 + rchunk];
  };
  auto MM16 = [&](s16x8* a, s16x8* b, int mq) {
#pragma unroll
    for (int ii = 0; ii < 4; ++ii)
#pragma unroll
      for (int j = 0; j < 4; ++j)
        acc[mq * 4 + ii][j] = __builtin_amdgcn_mfma_f32_16x16x32_bf16(
            a[ii], b[j], acc[mq * 4 + ii][j], 0, 0, 0);
  };
  auto MM8 = [&](s16x8* a, s16x8* b, int nh) {
#pragma unroll
    for (int ii = 0; ii < 4; ++ii)
#pragma unroll
      for (int j = 0; j < 2; ++j)
        acc[ii][nh * 2 + j] = __builtin_amdgcn_mfma_f32_16x16x32_bf16(
            a[ii], b[j], acc[ii][nh * 2 + j], 0, 0, 0);
  };

  // prologue: 3 units staged; drain U(0,k0); publish; prefetch first reads
  stA(0, 0, 0); stB(0, 0, 0);
  stA(0, 0, 1); stB(0, 0, 1);
  stA(1, 1, 0); stB(1, 1, 0);
  SCHEDB;
  if constexpr (MF == 8) asm volatile("s_waitcnt vmcnt(8)" ::: "memory");
  else                   asm volatile("s_waitcnt vmcnt(6)" ::: "memory");
  BAR;

  if constexpr (MF == 8) {
    s16x8 af0[4], af1[4], bf0[4], bf1[4];
    LDA4(af0, 0, 0, 0); LDB4(bf0, 0, 0);
    for (int kt = 0; kt < NT; ++kt) {
      const int bu = kt & 1;
      // ph0: MFMA(mq0,ks0) | prefetch A(mq1,ks0) | stage A(t+1,k1) | vmcnt(6)
      LGKM0; SCHEDB;
      __builtin_amdgcn_s_setprio(1); MM16(af0, bf0, 0); __builtin_amdgcn_s_setprio(0);
      LDA4(af1, bu, 0, 1);
      stA(kt + 1, bu ^ 1, 1);
      SCHEDB;
      asm volatile("s_waitcnt vmcnt(6)" ::: "memory");
      BAR;
      // ph1: MFMA(mq1,ks0) | prefetch B(ks1), A(mq0,ks1) | stage B(t+1,k1)
      LGKM0; SCHEDB;
      __builtin_amdgcn_s_setprio(1); MM16(af1, bf0, 1); __builtin_amdgcn_s_setprio(0);
      LDB4(bf1, bu, 1); LDA4(af0, bu, 1, 0);
      stB(kt + 1, bu ^ 1, 1);
      BAR;
      // ph2: MFMA(mq0,ks1) | prefetch A(mq1,ks1) | stage A(t+2,k0) | vmcnt(6)
      LGKM0; SCHEDB;
      __builtin_amdgcn_s_setprio(1); MM16(af0, bf1, 0); __builtin_amdgcn_s_setprio(0);
      LDA4(af1, bu, 1, 1);
      stA(kt + 2, bu, 0);
      SCHEDB;
      asm volatile("s_waitcnt vmcnt(6)" ::: "memory");
      BAR;
      // ph3: MFMA(mq1,ks1) | prefetch next tile (B ks0, A mq0 ks0) | stage B(t+2,k0)
      LGKM0; SCHEDB;
      __builtin_amdgcn_s_setprio(1); MM16(af1, bf1, 1); __builtin_amdgcn_s_setprio(0);
      if (kt + 1 < NT) { LDB4(bf0, bu ^ 1, 0); LDA4(af0, bu ^ 1, 0, 0); }
      stB(kt + 2, bu, 0);
      BAR;
    }
  } else {
    s16x8 af0[4], af1[4], bfA[2], bfB[2], bfC[2], bfD[2];
    LDA4(af0, 0, 0, 0); LDB2(bfA, 0, 0, 0);
    for (int kt = 0; kt < NT; ++kt) {
      const int bu = kt & 1;
      // ph0: MFMA(ks0,nh0) | prefetch B(ks0,nh1) | stage A(t+1,k1) | vmcnt(4)
      LGKM0; SCHEDB;
      __builtin_amdgcn_s_setprio(1); MM8(af0, bfA, 0); __builtin_amdgcn_s_setprio(0);
      LDB2(bfB, bu, 0, 1);
      stA(kt + 1, bu ^ 1, 1);
      SCHEDB;
      asm volatile("s_waitcnt vmcnt(4)" ::: "memory");
      BAR;
      // ph1: MFMA(ks0,nh1) | prefetch A(ks1), B(ks1,nh0) | stage B(t+1,k1)
      LGKM0; SCHEDB;
      __builtin_amdgcn_s_setprio(1); MM8(af0, bfB, 1); __builtin_amdgcn_s_setprio(0);
      LDA4(af1, bu, 1, 0); LDB2(bfC, bu, 1, 0);
      stB(kt + 1, bu ^ 1, 1);
      BAR;
      // ph2: MFMA(ks1,nh0) | prefetch B(ks1,nh1) | stage A(t+2,k0) | vmcnt(4)
      LGKM0; SCHEDB;
      __builtin_amdgcn_s_setprio(1); MM8(af1, bfC, 0); __builtin_amdgcn_s_setprio(0);
      LDB2(bfD, bu, 1, 1);
      stA(kt + 2, bu, 0);
      SCHEDB;
      asm volatile("s_waitcnt vmcnt(4)" ::: "memory");
      BAR;
      // ph3: MFMA(ks1,nh1) | prefetch next tile A(ks0), B(ks0,nh0) | stage B(t+2,k0)
      LGKM0; SCHEDB;
      __builtin_amdgcn_s_setprio(1); MM8(af1, bfD, 1); __builtin_amdgcn_s_setprio(0);
      if (kt + 1 < NT) { LDA4(af0, bu ^ 1, 0, 0); LDB2(bfA, bu ^ 1, 0, 0); }
      stB(kt + 2, bu, 0);
      BAR;
    }
  }

  // epilogue: C/D layout col=lane&15, row=(lane>>4)*4+q  [verified m89/m91]
  const int row0 = brow + wr * (MF * 16) + g4 * 4;
  const int col0 = bcol + wc * 64 + lr;
#pragma unroll
  for (int i = 0; i < MF; ++i) {
#pragma unroll
    for (int j = 0; j < 4; ++j) {
      int c_ = col0 + j * 16;
#pragma unroll
      for (int q = 0; q < 4; ++q) {
        int r_ = row0 + i * 16 + q;
        float v = acc[i][j][q];
        if constexpr (EPI == 0) {
          float p = v + bias0[c_];
          float gh = __expf(-fmaxf(p, 0.0f));
          float hd = gh * auxf[(size_t)r_ * 1024 + c_];
          out0b[(size_t)r_ * 1536 + 256 + c_] = f2b(hd);
        } else if constexpr (EPI == 1) {
          if (c_ < 1024) {
            out0b[(size_t)r_ * 1024 + c_] = f2b(sigm(v + bias0[c_]));
          } else {
            int jc = c_ - 1024;
            float rg = sigm(v + bias1[jc]);
            float hd = b2f(auxb[(size_t)r_ * 1536 + 256 + jc]);
            out1b[(size_t)r_ * 1024 + jc] = f2b(rg * hd);
          }
        } else {
          float ht = tanhf(v + bias0[c_]);
          float zz = b2f(aux2b[(size_t)r_ * 1024 + c_]);
          float hd = b2f(auxb[(size_t)r_ * 1536 + 256 + c_]);
          outf[(size_t)r_ * 1024 + c_] = (1.0f - zz) * hd + zz * ht;
        }
      }
    }
  }
}

// ---------------------------------------------------------------------------
extern "C" void kernel_launch(void* const* d_in, const int* in_sizes, int n_in,
                              void* d_out, int out_size, void* d_ws, size_t ws_size,
                              hipStream_t stream)
{
  const float* x     = (const float*)d_in[0];
  const float* m     = (const float*)d_in[1];
  const float* delta = (const float*)d_in[2];
  const float* h     = (const float*)d_in[3];
  const float* xlo   = (const float*)d_in[4];
  const float* xmean = (const float*)d_in[5];
  const float* Wgx   = (const float*)d_in[6];
  const float* bgx   = (const float*)d_in[7];
  const float* Wgh   = (const float*)d_in[8];
  const float* bgh   = (const float*)d_in[9];
  const float* Wxz   = (const float*)d_in[10];
  const float* Whz   = (const float*)d_in[11];
  const float* Wmz   = (const float*)d_in[12];
  const float* bmz   = (const float*)d_in[13];
  const float* Wxr   = (const float*)d_in[14];
  const float* Whr   = (const float*)d_in[15];
  const float* Wmr   = (const float*)d_in[16];
  const float* bmr   = (const float*)d_in[17];
  const float* Wxh   = (const float*)d_in[18];
  const float* Whh   = (const float*)d_in[19];
  const float* Wmh   = (const float*)d_in[20];
  const float* bmh   = (const float*)d_in[21];

  // workspace (bf16 elems): X1[8192,1536] Z[8192,1024] RH[8192,1024]
  //   WZR[2048,1536] WH[1024,1536] Dbf[8192,256] WGH[1024,256]  ~72.9MB
  u16* X1  = (u16*)d_ws;
  u16* Z   = X1 + (size_t)8192 * 1536;
  u16* RH  = Z  + (size_t)8192 * 1024;
  u16* WZR = RH + (size_t)8192 * 1024;
  u16* WH  = WZR + (size_t)2048 * 1536;
  u16* Dbf = WH + (size_t)1024 * 1536;
  u16* WGH = Dbf + (size_t)8192 * 256;

  float* out_h   = (float*)d_out;
  float* out_xlo = out_h + (size_t)8192 * 1024;

  pack_w<<<2432, 256, 0, stream>>>(Wxz, Whz, Wmz, Wxr, Whr, Wmr, Wxh, Whh, Wmh, Wgh, WZR, WH, WGH);
  elem_k<<<1024, 256, 0, stream>>>(x, m, delta, xlo, xmean, Wgx, bgx, X1, Dbf, out_xlo);
  // GEMM A: gamma_h -> h_decayed into X1[:,256:1280]   (M=8192,N=1024,K=256)
  gemm_bt<0, 4><<<dim3(4, 64), 512, 0, stream>>>(
      Dbf, nullptr, 256, WGH, bgh, nullptr, h, nullptr, nullptr, X1, nullptr, nullptr);
  // GEMM B: z -> Z ; r*h_decayed -> RH                 (M=8192,N=2048,K=1536)
  gemm_bt<1, 8><<<dim3(8, 32), 512, 0, stream>>>(
      X1, nullptr, 1536, WZR, bmz, bmr, nullptr, X1, nullptr, Z, RH, nullptr);
  // GEMM C: h_tilde + final blend -> h_new (f32)       (M=8192,N=1024,K=1536)
  gemm_bt<2, 4><<<dim3(4, 64), 512, 0, stream>>>(
      X1, RH, 1536, WH, bmh, nullptr, nullptr, X1, Z, nullptr, nullptr, out_h);
}

// Round 5
// 171.153 us; speedup vs baseline: 1.0512x; 1.0512x over previous
//
#include <hip/hip_runtime.h>
#include <cstdint>
#include <cstddef>

typedef unsigned short u16;
typedef __attribute__((ext_vector_type(8))) short s16x8;
typedef __attribute__((ext_vector_type(8))) u16 u16x8;
typedef __attribute__((ext_vector_type(4))) float f32x4;

#define DEV static __device__ __forceinline__
#define GPTR(p) (const __attribute__((address_space(1))) void*)(p)
#define LPTR(p) (__attribute__((address_space(3))) void*)(p)
#define SCHEDB __builtin_amdgcn_sched_barrier(0)
#define BAR __builtin_amdgcn_s_barrier()
#define SETP1 __builtin_amdgcn_s_setprio(1)
#define SETP0 __builtin_amdgcn_s_setprio(0)

DEV float b2f(u16 u) { union { unsigned i; float f; } c; c.i = ((unsigned)u) << 16; return c.f; }
DEV u16 f2b(float f) {
  union { float f; unsigned i; } c; c.f = f;
  unsigned r = (c.i + 0x7fffu + ((c.i >> 16) & 1u)) >> 16;
  return (u16)r;
}
DEV float sigm(float x) { return 1.0f / (1.0f + __expf(-x)); }

// ---------------------------------------------------------------------------
// Pack gate weights (f32 in) into concatenated bf16 [N,1536]:
//   WZR rows 0..1023    = [W_xz | W_hz | W_mz]
//   WZR rows 1024..2047 = [W_xr | W_hr | W_mr]
//   WH  rows 0..1023    = [W_xh | W_hh | W_mh]
// plus bf16 copy of W_gamma_h -> WGH [1024,256].
// ---------------------------------------------------------------------------
__global__ __launch_bounds__(256) void pack_w(
    const float* __restrict__ Wxz, const float* __restrict__ Whz, const float* __restrict__ Wmz,
    const float* __restrict__ Wxr, const float* __restrict__ Whr, const float* __restrict__ Wmr,
    const float* __restrict__ Wxh, const float* __restrict__ Whh, const float* __restrict__ Wmh,
    const float* __restrict__ Wgh,
    u16* __restrict__ WZR, u16* __restrict__ WH, u16* __restrict__ WGH)
{
  int t = blockIdx.x * 256 + threadIdx.x;
  const float* src;
  u16* dst;
  if (t < 589824) {
    int row = t / 192;
    int col = (t % 192) * 8;
    int rr = row & 1023;
    const float *wx, *wh, *wm;
    if (row < 1024)      { wx = Wxz; wh = Whz; wm = Wmz; }
    else if (row < 2048) { wx = Wxr; wh = Whr; wm = Wmr; }
    else                 { wx = Wxh; wh = Whh; wm = Wmh; }
    if (col < 256)       src = wx + rr * 256 + col;
    else if (col < 1280) src = wh + (size_t)rr * 1024 + (col - 256);
    else                 src = wm + rr * 256 + (col - 1280);
    dst = (row < 2048) ? (WZR + (size_t)row * 1536 + col)
                       : (WH + (size_t)(row - 2048) * 1536 + col);
  } else {
    int t2 = t - 589824;
    src = Wgh + t2 * 8;
    dst = WGH + t2 * 8;
  }
  f32x4 a = *(const f32x4*)src;
  f32x4 b = *(const f32x4*)(src + 4);
  u16x8 v;
#pragma unroll
  for (int j = 0; j < 4; ++j) { v[j] = f2b(a[j]); v[j + 4] = f2b(b[j]); }
  *(u16x8*)dst = v;
}

// ---------------------------------------------------------------------------
// Elementwise over [B,D]: gamma_x, imputation, x_hat -> X1/X2 cols 0..255 and
// 1280..1535 (m), bf16 delta copy, f32 x_last_obs_new.
// ---------------------------------------------------------------------------
__global__ __launch_bounds__(256) void elem_k(
    const float* __restrict__ x, const float* __restrict__ m, const float* __restrict__ delta,
    const float* __restrict__ xlo, const float* __restrict__ x_mean,
    const float* __restrict__ Wgx, const float* __restrict__ bgx,
    u16* __restrict__ X1, u16* __restrict__ X2, u16* __restrict__ Dbf,
    float* __restrict__ out_xlo)
{
  int t = blockIdx.x * 256 + threadIdx.x;
  int row = t >> 5;
  int col = (t & 31) * 8;
  size_t base = (size_t)row * 256 + col;
  u16x8 vxhat, vm16, vd16;
  f32x4 vlnew[2];
#pragma unroll
  for (int half = 0; half < 2; ++half) {
    f32x4 vx = *(const f32x4*)(x + base + half * 4);
    f32x4 vm = *(const f32x4*)(m + base + half * 4);
    f32x4 vd = *(const f32x4*)(delta + base + half * 4);
    f32x4 vl = *(const f32x4*)(xlo + base + half * 4);
    f32x4 vmean = *(const f32x4*)(x_mean + col + half * 4);
    f32x4 vwg = *(const f32x4*)(Wgx + col + half * 4);
    f32x4 vbg = *(const f32x4*)(bgx + col + half * 4);
#pragma unroll
    for (int j = 0; j < 4; ++j) {
      float mf = vm[j];
      float lnew = (mf > 0.5f) ? vx[j] : vl[j];
      vlnew[half][j] = lnew;
      float gx = __expf(-fmaxf(vd[j] * vwg[j] + vbg[j], 0.0f));
      float ximp = gx * lnew + (1.0f - gx) * vmean[j];
      float xhat = mf * vx[j] + (1.0f - mf) * ximp;
      vxhat[half * 4 + j] = f2b(xhat);
      vm16[half * 4 + j] = f2b(mf);
      vd16[half * 4 + j] = f2b(vd[j]);
    }
  }
  size_t r1536 = (size_t)row * 1536;
  *(u16x8*)(X1 + r1536 + col) = vxhat;
  *(u16x8*)(X2 + r1536 + col) = vxhat;
  *(u16x8*)(X1 + r1536 + 1280 + col) = vm16;
  *(u16x8*)(X2 + r1536 + 1280 + col) = vm16;
  *(u16x8*)(Dbf + base) = vd16;
  *(f32x4*)(out_xlo + base) = vlnew[0];
  *(f32x4*)(out_xlo + base + 4) = vlnew[1];
}

// ---------------------------------------------------------------------------
// r4-cadence pipelined bf16 GEMM with fully precomputed addressing:
//   C[M,N] = A[M,K] @ W[N,K]^T.  BN=256, BM=MF*32, BK=64, 8 waves (2Mx4N).
// 4 phases/tile, 1 barrier/phase, r4 stage ring (t+1:k1 at ph0/1, t+2:k0 at
// ph2/3), counted vmcnt(6)/(4) at ph0/ph2 (FIFO-verified, never 0).
// NEW vs r4 (VALU-cut): 2-tile unroll -> all slot indices compile-time;
// per-thread global stage pointers precomputed once, +128 elems per pair;
// stage k-offsets literal; unrolled no-stage tail instead of clamps; no
// explicit lgkmcnt (compiler emits minimal counted waits for its ds_reads).
// Swizzle (0-conflict, verified r2-r4): 16B chunk ^= (row>>1)&3; linear LDS
// dest + inverse-swizzled global src + swizzled ds_read. XCD-bijective map.
// EPI 0: h_decayed = exp(-relu(.+bgh)) * h      -> X1 cols 256..1279 (bf16)
// EPI 1: cols<1024: z=sigmoid -> Z ; cols>=1024: r*hdec -> X2 cols 256..1279
// EPI 2: h_new = (1-z)*hdec + z*tanh(.+bmh)     -> d_out (f32); A = X2
// ---------------------------------------------------------------------------
template<int EPI, int MF>
__global__ __launch_bounds__(512, 2) void gemm_bt(
    const u16* __restrict__ A, int K, const u16* __restrict__ W,
    const float* __restrict__ bias0, const float* __restrict__ bias1,
    const float* __restrict__ auxf,  // EPI0: h (f32)
    const u16* __restrict__ auxb,    // EPI2: X1 (hdec source, bf16)
    const u16* __restrict__ aux2b,   // EPI2: Z (bf16)
    u16* __restrict__ out0b,         // EPI0: X1 ; EPI1: Z
    u16* __restrict__ out1b,         // EPI1: X2
    float* __restrict__ outf)        // EPI2: d_out h_new
{
  constexpr int BM = MF * 32;
  constexpr int GX = (MF == 8) ? 8 : 4;
  constexpr int ASL = BM * 32;             // elems per A k-half slot
  constexpr int BSL = 256 * 32;
  __shared__ alignas(16) u16 As[2][2][ASL];
  __shared__ alignas(16) u16 Bs[2][2][BSL];

  const int tid = threadIdx.x;
  const int lane = tid & 63;
  const int wave = tid >> 6;
  const int wr = wave >> 2;                // 0..1 (M)
  const int wc = wave & 3;                 // 0..3 (N)

  // bijective XCD swizzle: 32 consecutive logical blocks per XCD
  const int d = blockIdx.y * GX + blockIdx.x;
  const int L = ((d & 7) << 5) | (d >> 3);
  const int brow = (L / GX) * BM;
  const int bcol = (L % GX) * 256;
  const int NT = K / 64;

  const int lr = lane & 15, g4 = lane >> 4;
  const int rc = (g4 ^ ((lr >> 1) & 3)) * 8;         // swizzled read chunk
  const int sr16 = lane >> 2;                        // staging row in 16-block
  const int scs = ((lane & 3) ^ ((sr16 >> 1) & 3)) * 8;

  f32x4 acc[MF][4];
#pragma unroll
  for (int i = 0; i < MF; ++i)
#pragma unroll
    for (int j = 0; j < 4; ++j) { f32x4 z0 = {0.f, 0.f, 0.f, 0.f}; acc[i][j] = z0; }

  // --- precomputed per-thread staging pointers (element units, k=0) ---
  const u16* aP0 = A + (size_t)(brow + wave * 16 + sr16) * K + scs;
  const u16* aP1 = (MF == 8) ? A + (size_t)(brow + (8 + wave) * 16 + sr16) * K + scs : nullptr;
  const u16* bP0 = W + (size_t)(bcol + wave * 16 + sr16) * K + scs;
  const u16* bP1 = W + (size_t)(bcol + (8 + wave) * 16 + sr16) * K + scs;
  u16* ldsA = &As[0][0][0] + wave * 512;   // + slot*ASL (+4096 for q=1)
  u16* ldsB = &Bs[0][0][0] + wave * 512;
  const u16* rdA = &As[0][0][0] + (wr * (BM / 2) + lr) * 32 + rc;
  const u16* rdB = &Bs[0][0][0] + (wc * 64 + lr) * 32 + rc;

  auto STA = [&](int slot, int koff) {
    __builtin_amdgcn_global_load_lds(GPTR(aP0 + koff), LPTR(ldsA + slot * ASL), 16, 0, 0);
    if constexpr (MF == 8)
      __builtin_amdgcn_global_load_lds(GPTR(aP1 + koff), LPTR(ldsA + slot * ASL + 4096), 16, 0, 0);
  };
  auto STB = [&](int slot, int koff) {
    __builtin_amdgcn_global_load_lds(GPTR(bP0 + koff), LPTR(ldsB + slot * BSL), 16, 0, 0);
    __builtin_amdgcn_global_load_lds(GPTR(bP1 + koff), LPTR(ldsB + slot * BSL + 4096), 16, 0, 0);
  };
  auto LDA4 = [&](s16x8* dst, int slot, int mq) {
    const u16* p = rdA + slot * ASL + mq * 2048;
#pragma unroll
    for (int ii = 0; ii < 4; ++ii) dst[ii] = *(const s16x8*)(p + ii * 512);
  };
  auto LDB4 = [&](s16x8* dst, int slot) {
    const u16* p = rdB + slot * BSL;
#pragma unroll
    for (int j = 0; j < 4; ++j) dst[j] = *(const s16x8*)(p + j * 512);
  };
  auto LDB2 = [&](s16x8* dst, int slot, int nh) {
    const u16* p = rdB + slot * BSL + nh * 1024;
#pragma unroll
    for (int j = 0; j < 2; ++j) dst[j] = *(const s16x8*)(p + j * 512);
  };
  auto MM16 = [&](s16x8* a, s16x8* b, int mq) {
#pragma unroll
    for (int ii = 0; ii < 4; ++ii)
#pragma unroll
      for (int j = 0; j < 4; ++j)
        acc[mq * 4 + ii][j] = __builtin_amdgcn_mfma_f32_16x16x32_bf16(
            a[ii], b[j], acc[mq * 4 + ii][j], 0, 0, 0);
  };
  auto MM8 = [&](s16x8* a, s16x8* b, int nh) {
#pragma unroll
    for (int ii = 0; ii < 4; ++ii)
#pragma unroll
      for (int j = 0; j < 2; ++j)
        acc[ii][nh * 2 + j] = __builtin_amdgcn_mfma_f32_16x16x32_bf16(
            a[ii], b[j], acc[ii][nh * 2 + j], 0, 0, 0);
  };

  // prologue: stage U(0,k0) U(0,k1) U(1,k0); drain oldest; publish; prefetch
  STA(0, 0);  STB(0, 0);
  STA(1, 32); STB(1, 32);
  STA(2, 64); STB(2, 64);
  if constexpr (MF == 8) asm volatile("s_waitcnt vmcnt(8)" ::: "memory");
  else                   asm volatile("s_waitcnt vmcnt(6)" ::: "memory");
  BAR;

  if constexpr (MF == 8) {
    s16x8 af0[4], af1[4], bf0[4], bf1[4];
    LDA4(af0, 0, 0); LDB4(bf0, 0);
    // body: slots s0,s1 (this tile), n0 (next tile k0), o1 (t+1 k1 target)
    auto tile8 = [&](int s0, int s1, int n0, int o1, int k1o, int k2o, bool S1, bool S2) {
      // ph0
      SETP1; MM16(af0, bf0, 0); SETP0;
      LDA4(af1, s0, 1);
      if (S1) STA(o1, k1o);
      SCHEDB; asm volatile("s_waitcnt vmcnt(6)" ::: "memory"); BAR;
      // ph1
      SETP1; MM16(af1, bf0, 1); SETP0;
      LDB4(bf1, s1); LDA4(af0, s1, 0);
      if (S1) STB(o1, k1o);
      SCHEDB; BAR;
      // ph2
      SETP1; MM16(af0, bf1, 0); SETP0;
      LDA4(af1, s1, 1);
      if (S2) STA(s0, k2o);
      SCHEDB; asm volatile("s_waitcnt vmcnt(6)" ::: "memory"); BAR;
      // ph3
      SETP1; MM16(af1, bf1, 1); SETP0;
      LDB4(bf0, n0); LDA4(af0, n0, 0);
      if (S2) STB(s0, k2o);
      SCHEDB; BAR;
    };
    for (int kt = 0; kt < NT - 2; kt += 2) {
      tile8(0, 1, 2, 3, 96, 128, true, true);
      tile8(2, 3, 0, 1, 160, 192, true, true);
      aP0 += 128; aP1 += 128; bP0 += 128; bP1 += 128;
    }
    tile8(0, 1, 2, 3, 96, 128, true, false);
    tile8(2, 3, 0, 1, 160, 192, false, false);
  } else {
    s16x8 af0[4], af1[4], bfA[2], bfB[2], bfC[2], bfD[2];
    LDA4(af0, 0, 0); LDB2(bfA, 0, 0);
    auto tile4 = [&](int s0, int s1, int n0, int o1, int k1o, int k2o, bool S1, bool S2) {
      // ph0
      SETP1; MM8(af0, bfA, 0); SETP0;
      LDB2(bfB, s0, 1);
      if (S1) STA(o1, k1o);
      SCHEDB; asm volatile("s_waitcnt vmcnt(4)" ::: "memory"); BAR;
      // ph1
      SETP1; MM8(af0, bfB, 1); SETP0;
      LDA4(af1, s1, 0); LDB2(bfC, s1, 0);
      if (S1) STB(o1, k1o);
      SCHEDB; BAR;
      // ph2
      SETP1; MM8(af1, bfC, 0); SETP0;
      LDB2(bfD, s1, 1);
      if (S2) STA(s0, k2o);
      SCHEDB; asm volatile("s_waitcnt vmcnt(4)" ::: "memory"); BAR;
      // ph3
      SETP1; MM8(af1, bfD, 1); SETP0;
      LDA4(af0, n0, 0); LDB2(bfA, n0, 0);
      if (S2) STB(s0, k2o);
      SCHEDB; BAR;
    };
    for (int kt = 0; kt < NT - 2; kt += 2) {
      tile4(0, 1, 2, 3, 96, 128, true, true);
      tile4(2, 3, 0, 1, 160, 192, true, true);
      aP0 += 128; bP0 += 128; bP1 += 128;
    }
    tile4(0, 1, 2, 3, 96, 128, true, false);
    tile4(2, 3, 0, 1, 160, 192, false, false);
  }

  // epilogue: C/D layout col=lane&15, row=(lane>>4)*4+q  [verified m89/m91]
  const int row0 = brow + wr * (MF * 16) + g4 * 4;
  const int col0 = bcol + wc * 64 + lr;
#pragma unroll
  for (int i = 0; i < MF; ++i) {
#pragma unroll
    for (int j = 0; j < 4; ++j) {
      int c_ = col0 + j * 16;
#pragma unroll
      for (int q = 0; q < 4; ++q) {
        int r_ = row0 + i * 16 + q;
        float v = acc[i][j][q];
        if constexpr (EPI == 0) {
          float p = v + bias0[c_];
          float gh = __expf(-fmaxf(p, 0.0f));
          float hd = gh * auxf[(size_t)r_ * 1024 + c_];
          out0b[(size_t)r_ * 1536 + 256 + c_] = f2b(hd);
        } else if constexpr (EPI == 1) {
          if (c_ < 1024) {
            out0b[(size_t)r_ * 1024 + c_] = f2b(sigm(v + bias0[c_]));
          } else {
            int jc = c_ - 1024;
            float rg = sigm(v + bias1[jc]);
            float hd = b2f(auxb[(size_t)r_ * 1536 + 256 + jc]);
            out1b[(size_t)r_ * 1536 + 256 + jc] = f2b(rg * hd);
          }
        } else {
          float ht = tanhf(v + bias0[c_]);
          float zz = b2f(aux2b[(size_t)r_ * 1024 + c_]);
          float hd = b2f(auxb[(size_t)r_ * 1536 + 256 + c_]);
          outf[(size_t)r_ * 1024 + c_] = (1.0f - zz) * hd + zz * ht;
        }
      }
    }
  }
}

// ---------------------------------------------------------------------------
extern "C" void kernel_launch(void* const* d_in, const int* in_sizes, int n_in,
                              void* d_out, int out_size, void* d_ws, size_t ws_size,
                              hipStream_t stream)
{
  const float* x     = (const float*)d_in[0];
  const float* m     = (const float*)d_in[1];
  const float* delta = (const float*)d_in[2];
  const float* h     = (const float*)d_in[3];
  const float* xlo   = (const float*)d_in[4];
  const float* xmean = (const float*)d_in[5];
  const float* Wgx   = (const float*)d_in[6];
  const float* bgx   = (const float*)d_in[7];
  const float* Wgh   = (const float*)d_in[8];
  const float* bgh   = (const float*)d_in[9];
  const float* Wxz   = (const float*)d_in[10];
  const float* Whz   = (const float*)d_in[11];
  const float* Wmz   = (const float*)d_in[12];
  const float* bmz   = (const float*)d_in[13];
  const float* Wxr   = (const float*)d_in[14];
  const float* Whr   = (const float*)d_in[15];
  const float* Wmr   = (const float*)d_in[16];
  const float* bmr   = (const float*)d_in[17];
  const float* Wxh   = (const float*)d_in[18];
  const float* Whh   = (const float*)d_in[19];
  const float* Wmh   = (const float*)d_in[20];
  const float* bmh   = (const float*)d_in[21];

  // workspace (bf16): X1[8192,1536] X2[8192,1536] Z[8192,1024]
  //   WZR[2048,1536] WH[1024,1536] Dbf[8192,256] WGH[1024,256]  ~81.3MB
  u16* X1  = (u16*)d_ws;
  u16* X2  = X1 + (size_t)8192 * 1536;
  u16* Z   = X2 + (size_t)8192 * 1536;
  u16* WZR = Z  + (size_t)8192 * 1024;
  u16* WH  = WZR + (size_t)2048 * 1536;
  u16* Dbf = WH + (size_t)1024 * 1536;
  u16* WGH = Dbf + (size_t)8192 * 256;

  float* out_h   = (float*)d_out;
  float* out_xlo = out_h + (size_t)8192 * 1024;

  pack_w<<<2432, 256, 0, stream>>>(Wxz, Whz, Wmz, Wxr, Whr, Wmr, Wxh, Whh, Wmh, Wgh, WZR, WH, WGH);
  elem_k<<<1024, 256, 0, stream>>>(x, m, delta, xlo, xmean, Wgx, bgx, X1, X2, Dbf, out_xlo);
  // GEMM A: gamma_h -> h_decayed into X1[:,256:1280]   (M=8192,N=1024,K=256)
  gemm_bt<0, 4><<<dim3(4, 64), 512, 0, stream>>>(
      Dbf, 256, WGH, bgh, nullptr, h, nullptr, nullptr, X1, nullptr, nullptr);
  // GEMM B: z -> Z ; r*h_decayed -> X2[:,256:1280]     (M=8192,N=2048,K=1536)
  gemm_bt<1, 8><<<dim3(8, 32), 512, 0, stream>>>(
      X1, 1536, WZR, bmz, bmr, nullptr, X1, nullptr, Z, X2, nullptr);
  // GEMM C: h_tilde + final blend -> h_new (f32)       (M=8192,N=1024,K=1536)
  gemm_bt<2, 4><<<dim3(4, 64), 512, 0, stream>>>(
      X2, 1536, WH, bmh, nullptr, nullptr, X1, Z, nullptr, nullptr, out_h);
}